// Round 12
// baseline (53.722 us; speedup 1.0000x reference)
//
#include <hip/hip_runtime.h>
#include <math.h>

#define EDIM 128
#define NATOM 128
#define NBATCH 512
#define THREADS 512
#define ROWLEN 257

typedef __attribute__((ext_vector_type(8))) short bf16x8;           // 8 bf16 (4 VGPRs)
typedef __attribute__((ext_vector_type(4))) float f32x4;            // MFMA C/D frag
typedef __attribute__((ext_vector_type(4))) unsigned short u16x4;   // 8B packed bf16

__device__ __forceinline__ unsigned short f2bf(float f) {       // RNE float->bf16
    unsigned u = __float_as_uint(f);
    u += 0x7FFFu + ((u >> 16) & 1u);
    return (unsigned short)(u >> 16);
}
// 1-op RNE f32->bf16 (single value)
__device__ __forceinline__ unsigned short cvt1(float x) {
    unsigned r;
    asm("v_cvt_pk_bf16_f32 %0, %1, %1" : "=v"(r) : "v"(x));
    return (unsigned short)r;
}
// 2-in-1 pack: dst[15:0]=bf16(a0), dst[31:16]=bf16(a1) -> memory order a0,a1
__device__ __forceinline__ unsigned cvt2(float a0, float a1) {
    unsigned r;
    asm("v_cvt_pk_bf16_f32 %0, %1, %2" : "=v"(r) : "v"(a0), "v"(a1));
    return r;
}
__device__ __forceinline__ float fast_ssp(float x) {            // softplus(x)-log2, stable
    return fmaxf(x, 0.f) + __logf(1.f + __expf(-fabsf(x))) - 0.69314718055994531f;
}
// XOR swizzle on a row-major [128][256B] bf16 plane (bits 4..6 of byte offset);
// consistent for b32 stores and b128 reads. phase decorrelates X vs K plane.
__device__ __forceinline__ int swzp(int row, int cbyte, int phase) {
    return row * 256 + ((cbyte ^ phase) ^ ((row & 7) << 4));
}

#define PH 0
#define QH 32768

// W -> bf16 (plain RNE; accuracy margin covers dropped lo-term: absmax 4.0 / thr 76.5)
__global__ void wcvt_kernel(const float* __restrict__ Wx,
                            const float* __restrict__ Wk,
                            unsigned short* __restrict__ ws) {
    int g = blockIdx.x * 256 + threadIdx.x;          // 0..32767
    const float* src = (g < 16384) ? Wx : Wk;
    ws[g] = f2bf(src[g & 16383]);
}

__global__ void __launch_bounds__(THREADS, 4)   // 4 waves/EU -> 2 blocks/CU, VGPR cap 128
gen_actions_kernel(const float* __restrict__ kx,
                   const float* __restrict__ pos,
                   const float* __restrict__ mask,
                   const float* __restrict__ scale_ptr,
                   const float* __restrict__ evala,
                   const float* __restrict__ bx,
                   const float* __restrict__ bk,
                   const unsigned short* __restrict__ ws,
                   float* __restrict__ out)
{
    extern __shared__ char lds[];        // act_x/X plane (32KB) + act_k/K plane (32KB)
    __shared__ f32x4 posQs[NATOM];       // {x, y, z, log_std} -> 1 ds_read_b128 per atom
    __shared__ float amBs[NATOM * 3];
    __shared__ float redBs[2];
    __shared__ int   cntBs[2];

    const int b = blockIdx.x;
    const int t = threadIdx.x;
    const int lane = t & 63;
    const int w = t >> 6;            // wave 0..7
    const int wrb = w >> 2;          // M tile base: this wave owns tiles wrb, wrb+2
    const int wc = w & 3;            // N tile (atoms-j), 0..3
    const int l15 = lane & 15;
    const int l4  = lane >> 4;

    // ---------------- P1: block count, pos+log_std pack, zero accumulators
    if (t < NATOM) {
        float m = mask[b * NATOM + t];
        unsigned long long bal = __ballot(m > 0.5f);
        if ((t & 63) == 0) cntBs[t >> 6] = __popcll(bal);
        const float* p = pos + ((size_t)b * NATOM + t) * 3;
        f32x4 q;
        q[0] = p[0]; q[1] = p[1]; q[2] = p[2];
        q[3] = kx[(size_t)b * (NATOM * ROWLEN) + t * ROWLEN + 2 * EDIM];  // log_std
        posQs[t] = q;
    }
    if (t < NATOM * 3) amBs[t] = 0.f;

    // ---------------- P2: coalesced kx stream -> bf16 activation planes.
    // Per-wave redundant count (no barrier) lets us skip rows >= ceil32(count) —
    // exactly the rows no GEMM/gram tile reads. Lane handles adjacent element
    // pair (2e,2e+1): one cvt_pk + one ds_write_b32 per half-row (was 2 stores).
    {
        float mA = mask[b * NATOM + lane];
        float mB = mask[b * NATOM + 64 + lane];
        int cnt = __popcll(__ballot(mA > 0.5f)) + __popcll(__ballot(mB > 0.5f));
        const int cnt32 = (cnt + 31) & ~31;        // wave-uniform
        const float* kb = kx + (size_t)b * (NATOM * ROWLEN);
        #pragma unroll 4
        for (int rr2 = 0; rr2 < 16; ++rr2) {
            const int row = rr2 * 8 + w;
            if (row < cnt32) {                     // wave-uniform skip
                const float* src = kb + row * ROWLEN;
                float x0 = src[2 * lane];
                float x1 = src[2 * lane + 1];
                float y0 = src[128 + 2 * lane];
                float y1 = src[128 + 2 * lane + 1];
                unsigned pa = cvt2(fast_ssp(x0), fast_ssp(x1));
                unsigned pc = cvt2(fmaxf(y0, 0.f), fmaxf(y1, 0.f));
                *(unsigned*)(lds + PH + swzp(row, 4 * lane, 0))  = pa;
                *(unsigned*)(lds + QH + swzp(row, 4 * lane, 64)) = pc;
            }
        }
    }
    __syncthreads();                 // B1: planes + count + pos ready
    const int count = cntBs[0] + cntBs[1];   // mask is a contiguous prefix

    const int n0 = wc * 32;          // atom tile base (N-dim), shared by both p-tiles
    const bool nact = (n0 < count);

    // ---------------- P3: X then K GEMM (bf16 W), per-mat write-back (16 regs
    // held across barrier); mat1 MFMAs overlap X-write drain.
    #define GEMM_MAT(MAT, PLANE, PHASE, WSOFF, BIAS)                                    \
    {                                                                                   \
        u16x4 pk[2][2][2];                                                              \
        if (nact) {                                                                     \
            const char* act = lds + PLANE;                                              \
            const unsigned short* WH = ws + WSOFF;                                      \
            f32x4 acc[2][2][2] = {};                                                    \
            for (int ks = 0; ks < 4; ++ks) {                                            \
                const int e0 = ks * 32 + l4 * 8;                                        \
                bf16x8 ah[2];                                                           \
                _Pragma("unroll")                                                       \
                for (int nf = 0; nf < 2; ++nf)                                          \
                    ah[nf] = *(const bf16x8*)(act + swzp(n0 + nf * 16 + l15, e0 * 2, PHASE)); \
                _Pragma("unroll")                                                       \
                for (int p = 0; p < 2; ++p) {                                           \
                    _Pragma("unroll")                                                   \
                    for (int mf = 0; mf < 2; ++mf) {                                    \
                        int orow = (wrb + 2 * p) * 32 + mf * 16 + l15;                  \
                        bf16x8 wh = *(const bf16x8*)(WH + orow * 128 + e0);             \
                        _Pragma("unroll")                                               \
                        for (int nf = 0; nf < 2; ++nf)                                  \
                            acc[p][mf][nf] = __builtin_amdgcn_mfma_f32_16x16x32_bf16(wh, ah[nf], acc[p][mf][nf], 0, 0, 0); \
                    }                                                                   \
                }                                                                       \
            }                                                                           \
            _Pragma("unroll")                                                           \
            for (int p = 0; p < 2; ++p)                                                 \
                _Pragma("unroll")                                                       \
                for (int mf = 0; mf < 2; ++mf) {                                        \
                    int ob = (wrb + 2 * p) * 32 + mf * 16 + l4 * 4;                     \
                    f32x4 b4 = *(const f32x4*)(BIAS + ob);                              \
                    _Pragma("unroll")                                                   \
                    for (int nf = 0; nf < 2; ++nf) {                                    \
                        u16x4 hs;                                                       \
                        _Pragma("unroll")                                               \
                        for (int r = 0; r < 4; ++r) hs[r] = cvt1(acc[p][mf][nf][r] + b4[r]); \
                        pk[p][mf][nf] = hs;                                             \
                    }                                                                   \
                }                                                                       \
        }                                                                               \
        __syncthreads();   /* all reads of this act plane complete */                   \
        if (nact) {                                                                     \
            _Pragma("unroll")                                                           \
            for (int p = 0; p < 2; ++p)                                                 \
                _Pragma("unroll")                                                       \
                for (int mf = 0; mf < 2; ++mf) {                                        \
                    int ob2 = ((wrb + 2 * p) * 32 + mf * 16 + l4 * 4) * 2;              \
                    _Pragma("unroll")                                                   \
                    for (int nf = 0; nf < 2; ++nf) {                                    \
                        int jrow = n0 + nf * 16 + l15;                                  \
                        *(u16x4*)(lds + PLANE + swzp(jrow, ob2, PHASE)) = pk[p][mf][nf]; \
                    }                                                                   \
                }                                                                       \
        }                                                                               \
    }

    GEMM_MAT(0, PH, 0,  0,     bx)      // X written to PH
    GEMM_MAT(1, QH, 64, 16384, bk)      // K written to QH
    __syncthreads();                 // B3: X,K planes ready

    // ---------------- P4: Grams G = X@X^T, K@K^T (bf16) + pairwise epilogue
    const int n0g = n0;
    if (n0g < count) {
        f32x4 gx[2][2][2] = {}, gk[2][2][2] = {};
        for (int ks = 0; ks < 4; ++ks) {           // both grams, B-frags shared across p
            const int e0b = (ks * 32 + l4 * 8) * 2;
            bf16x8 bX[2], bK[2];
            #pragma unroll
            for (int nf = 0; nf < 2; ++nf) {
                bX[nf] = *(const bf16x8*)(lds + PH + swzp(n0g + nf * 16 + l15, e0b, 0));
                bK[nf] = *(const bf16x8*)(lds + QH + swzp(n0g + nf * 16 + l15, e0b, 64));
            }
            #pragma unroll
            for (int p = 0; p < 2; ++p) {
                const int m0g = (wrb + 2 * p) * 32;
                if (m0g < count) {
                    #pragma unroll
                    for (int mf = 0; mf < 2; ++mf) {
                        int irow = m0g + mf * 16 + l15;
                        bf16x8 aX = *(const bf16x8*)(lds + PH + swzp(irow, e0b, 0));
                        bf16x8 aK = *(const bf16x8*)(lds + QH + swzp(irow, e0b, 64));
                        #pragma unroll
                        for (int nf = 0; nf < 2; ++nf) {
                            gx[p][mf][nf] = __builtin_amdgcn_mfma_f32_16x16x32_bf16(aX, bX[nf], gx[p][mf][nf], 0, 0, 0);
                            gk[p][mf][nf] = __builtin_amdgcn_mfma_f32_16x16x32_bf16(aK, bK[nf], gk[p][mf][nf], 0, 0, 0);
                        }
                    }
                }
            }
        }
        // pairwise epilogue: i-outer (1 b128 posQ read per i), nf-inner; fast
        // rcp/sqrt (error ~1e-7 vs absmax margin 76.5/4.0).
        const float inv_e = 0.08838834764831845f;            // 1/sqrt(128)
        float am[2][3] = {};
        f32x4 pj4[2];
        bool jv[2];
        #pragma unroll
        for (int nf = 0; nf < 2; ++nf) {
            const int j = n0g + nf * 16 + l15;
            jv[nf] = (j < count);
            pj4[nf] = posQs[j];
        }
        #pragma unroll
        for (int p = 0; p < 2; ++p) {
            const int m0g = (wrb + 2 * p) * 32;
            if (m0g < count) {
                #pragma unroll
                for (int mf = 0; mf < 2; ++mf) {
                    #pragma unroll
                    for (int r = 0; r < 4; ++r) {
                        const int i = m0g + mf * 16 + l4 * 4 + r;
                        f32x4 pi4 = posQs[i];
                        const bool iv = (i < count);
                        #pragma unroll
                        for (int nf = 0; nf < 2; ++nf) {
                            float dx = pj4[nf][0] - pi4[0];
                            float dy = pj4[nf][1] - pi4[1];
                            float dz = pj4[nf][2] - pi4[2];
                            float r2 = fmaf(dx, dx, fmaf(dy, dy, dz * dz)) + 1e-16f;
                            float rr = __builtin_amdgcn_sqrtf(r2);
                            bool ok = jv[nf] && iv && (rr < 5.0f);
                            float fc = ok ? (0.5f * (__cosf(rr * 0.62831853071795865f) + 1.f)) : 0.f;
                            float xs = fmaf(gx[p][mf][nf][r], -0.044194173824159216f, rr * 0.5f);
                            float fv = xs * (gk[p][mf][nf][r] * inv_e) * fc;
                            float wgt = fv * __builtin_amdgcn_rcpf(rr + 1e-8f);
                            am[nf][0] = fmaf(dx, wgt, am[nf][0]);
                            am[nf][1] = fmaf(dy, wgt, am[nf][1]);
                            am[nf][2] = fmaf(dz, wgt, am[nf][2]);
                        }
                    }
                }
            }
        }
        #pragma unroll
        for (int nf = 0; nf < 2; ++nf) {
            float amx = am[nf][0], amy = am[nf][1], amz = am[nf][2];
            amx += __shfl_xor(amx, 16); amx += __shfl_xor(amx, 32);
            amy += __shfl_xor(amy, 16); amy += __shfl_xor(amy, 32);
            amz += __shfl_xor(amz, 16); amz += __shfl_xor(amz, 32);
            if (l4 == 0 && jv[nf]) {
                const int j = n0g + nf * 16 + l15;
                atomicAdd(&amBs[j * 3 + 0], amx);
                atomicAdd(&amBs[j * 3 + 1], amy);
                atomicAdd(&amBs[j * 3 + 2], amz);
            }
        }
    }
    __syncthreads();                 // B4: actions_mean complete

    // ---------------- P5: outputs
    if (t < 96) {
        f32x4 ev4 = *(const f32x4*)(evala + (size_t)b * 384 + t * 4);
        f32x4 o4;
        #pragma unroll
        for (int c = 0; c < 4; ++c) {
            int atom = (t * 4 + c) / 3;
            o4[c] = (atom < count) ? ev4[c] : 0.f;
        }
        *(f32x4*)(out + (size_t)b * 384 + t * 4) = o4;
    }
    float lp = 0.f;
    if (t < NATOM && t < count) {
        const float* ev = evala + ((size_t)b * NATOM + t) * 3;
        float e0v = ev[0], e1v = ev[1], e2v = ev[2];
        float scale = scale_ptr[0];
        f32x4 q = posQs[t];
        float ax = amBs[t * 3 + 0], ay = amBs[t * 3 + 1], az = amBs[t * 3 + 2];
        float nrm = sqrtf(fmaf(ax, ax, fmaf(ay, ay, az * az)) + 1e-16f) + 1e-8f;
        float qe = __expf(-2.f * nrm);
        float th = (1.f - qe) / (1.f + qe);
        float sc = th / nrm * scale;
        float ls = fminf(fmaxf(q[3], -20.f), 2.f);
        float sig = __expf(ls) * scale;
        float sinv = 1.f / sig;
        float zx = (e0v - ax * sc) * sinv;
        float zy = (e1v - ay * sc) * sinv;
        float zz = (e2v - az * sc) * sinv;
        lp = -0.5f * (zx * zx + zy * zy + zz * zz) - 3.f * __logf(sig)
             - 3.f * 0.91893853320467274f;
    }
    #pragma unroll
    for (int off = 32; off > 0; off >>= 1) lp += __shfl_down(lp, off);
    if (t == 0)  redBs[0] = lp;
    if (t == 64) redBs[1] = lp;
    __syncthreads();                 // B5
    if (t == 0) out[(size_t)NBATCH * NATOM * 3 + b] = redBs[0] + redBs[1];
}

extern "C" void kernel_launch(void* const* d_in, const int* in_sizes, int n_in,
                              void* d_out, int out_size, void* d_ws, size_t ws_size,
                              hipStream_t stream) {
    const float* kx    = (const float*)d_in[0];
    const float* pos   = (const float*)d_in[1];
    const float* mask  = (const float*)d_in[2];
    const float* scale = (const float*)d_in[3];
    const float* ev    = (const float*)d_in[4];
    const float* Wx    = (const float*)d_in[5];
    const float* bx    = (const float*)d_in[6];
    const float* Wk    = (const float*)d_in[7];
    const float* bk    = (const float*)d_in[8];
    float* out = (float*)d_out;
    unsigned short* ws = (unsigned short*)d_ws;

    // W -> bf16 (64KB in d_ws), recomputed each launch (deterministic)
    hipLaunchKernelGGL(wcvt_kernel, dim3(128), dim3(256), 0, stream, Wx, Wk, ws);

    const size_t shbytes = 65536;   // 2 planes x 32KB dynamic LDS -> 2 blocks/CU
    (void)hipFuncSetAttribute((const void*)gen_actions_kernel,
                              hipFuncAttributeMaxDynamicSharedMemorySize,
                              (int)shbytes);
    hipLaunchKernelGGL(gen_actions_kernel, dim3(NBATCH), dim3(THREADS), shbytes, stream,
                       kx, pos, mask, scale, ev, bx, bk, ws, out);
}

// Round 13
// 51.983 us; speedup vs baseline: 1.0334x; 1.0334x over previous
//
#include <hip/hip_runtime.h>
#include <math.h>

#define EDIM 128
#define NATOM 128
#define NBATCH 512
#define THREADS 1024
#define ROWLEN 257

typedef __attribute__((ext_vector_type(8))) short bf16x8;           // 8 bf16 (4 VGPRs)
typedef __attribute__((ext_vector_type(4))) float f32x4;            // MFMA C/D frag
typedef __attribute__((ext_vector_type(4))) unsigned short u16x4;   // 8B packed bf16

__device__ __forceinline__ unsigned short f2bf(float f) {       // RNE float->bf16
    unsigned u = __float_as_uint(f);
    u += 0x7FFFu + ((u >> 16) & 1u);
    return (unsigned short)(u >> 16);
}
// 1-op RNE f32->bf16 (single value)
__device__ __forceinline__ unsigned short cvt1(float x) {
    unsigned r;
    asm("v_cvt_pk_bf16_f32 %0, %1, %1" : "=v"(r) : "v"(x));
    return (unsigned short)r;
}
// 2-in-1 pack: dst[15:0]=bf16(a0), dst[31:16]=bf16(a1) -> memory order a0,a1
__device__ __forceinline__ unsigned cvt2(float a0, float a1) {
    unsigned r;
    asm("v_cvt_pk_bf16_f32 %0, %1, %2" : "=v"(r) : "v"(a0), "v"(a1));
    return r;
}
__device__ __forceinline__ float fast_ssp(float x) {            // softplus(x)-log2, stable
    return fmaxf(x, 0.f) + __logf(1.f + __expf(-fabsf(x))) - 0.69314718055994531f;
}
// XOR swizzle on a row-major [128][256B] bf16 plane (bits 4..6 of byte offset);
// consistent for b32 stores and b128 reads. phase decorrelates X vs K plane.
__device__ __forceinline__ int swzp(int row, int cbyte, int phase) {
    return row * 256 + ((cbyte ^ phase) ^ ((row & 7) << 4));
}

#define PH 0
#define QH 32768

// W -> bf16 (plain RNE; accuracy margin covers dropped lo-term: absmax 4.0 / thr 76.5)
__global__ void wcvt_kernel(const float* __restrict__ Wx,
                            const float* __restrict__ Wk,
                            unsigned short* __restrict__ ws) {
    int g = blockIdx.x * 256 + threadIdx.x;          // 0..32767
    const float* src = (g < 16384) ? Wx : Wk;
    ws[g] = f2bf(src[g & 16383]);
}

// 16 waves as 4x4 tile grid; each wave owns ONE 32x32 output tile -> accumulator
// footprint 16 f32 per phase. launch_bounds(,8) pins total (VGPR+AGPR) <= 64
// -> 8 waves/SIMD -> 2 blocks (32 waves) per CU WITHOUT spill.
__global__ void __launch_bounds__(THREADS, 8)
gen_actions_kernel(const float* __restrict__ kx,
                   const float* __restrict__ pos,
                   const float* __restrict__ mask,
                   const float* __restrict__ scale_ptr,
                   const float* __restrict__ evala,
                   const float* __restrict__ bx,
                   const float* __restrict__ bk,
                   const unsigned short* __restrict__ ws,
                   float* __restrict__ out)
{
    extern __shared__ char lds[];        // act_x/X plane (32KB) + act_k/K plane (32KB)
    __shared__ float posXs[NATOM], posYs[NATOM], posZs[NATOM], lsBs[NATOM];
    __shared__ float amBs[NATOM * 3];
    __shared__ float redBs[2];
    __shared__ int   cntBs[2];

    const int b = blockIdx.x;
    const int t = threadIdx.x;
    const int lane = t & 63;
    const int w = t >> 6;            // wave 0..15
    const int wr = w >> 2;           // M tile (features / atoms-i), 0..3
    const int wc = w & 3;            // N tile (atoms-j), 0..3
    const int l15 = lane & 15;
    const int l4  = lane >> 4;

    // ---------------- P1: count, positions, log_std, zero accumulators
    if (t < NATOM) {
        float m = mask[b * NATOM + t];
        unsigned long long bal = __ballot(m > 0.5f);
        if ((t & 63) == 0) cntBs[t >> 6] = __popcll(bal);
        const float* p = pos + ((size_t)b * NATOM + t) * 3;
        posXs[t] = p[0]; posYs[t] = p[1]; posZs[t] = p[2];
        lsBs[t] = kx[(size_t)b * (NATOM * ROWLEN) + t * ROWLEN + 2 * EDIM];
    }
    if (t < NATOM * 3) amBs[t] = 0.f;

    // ---------------- P2: coalesced kx stream -> bf16 activation planes.
    // Per-wave redundant count (no barrier) skips rows >= ceil32(count) — exactly
    // the rows no tile reads. Lane handles adjacent pair (2e,2e+1): one cvt_pk +
    // one ds_write_b32 per plane per row. 8 rows/wave.
    {
        float mA = mask[b * NATOM + lane];
        float mB = mask[b * NATOM + 64 + lane];
        int cnt = __popcll(__ballot(mA > 0.5f)) + __popcll(__ballot(mB > 0.5f));
        const int cnt32 = (cnt + 31) & ~31;        // wave-uniform
        const float* kb = kx + (size_t)b * (NATOM * ROWLEN);
        #pragma unroll 4
        for (int r8 = 0; r8 < 8; ++r8) {
            const int row = r8 * 16 + w;
            if (row < cnt32) {                     // wave-uniform skip
                const float* src = kb + row * ROWLEN;
                float x0 = src[2 * lane];
                float x1 = src[2 * lane + 1];
                float y0 = src[128 + 2 * lane];
                float y1 = src[128 + 2 * lane + 1];
                unsigned pa = cvt2(fast_ssp(x0), fast_ssp(x1));
                unsigned pc = cvt2(fmaxf(y0, 0.f), fmaxf(y1, 0.f));
                *(unsigned*)(lds + PH + swzp(row, 4 * lane, 0))  = pa;
                *(unsigned*)(lds + QH + swzp(row, 4 * lane, 64)) = pc;
            }
        }
    }
    __syncthreads();                 // B1: planes + count + pos ready
    const int count = cntBs[0] + cntBs[1];   // mask is a contiguous prefix

    const int m0 = wr * 32;          // feature-tile base (GEMM) / atom-i tile (gram)
    const int n0 = wc * 32;          // atom-tile base (N-dim)
    const bool nact = (n0 < count);

    // ---------------- P3 (merged): X and K GEMMs -> packed frags, one barrier,
    // then both writes. Per-mat acc is 16 f32; both packs held = 16 regs.
    u16x4 xpk[2][2], kpk[2][2];
    if (nact) {
        #pragma unroll
        for (int mat = 0; mat < 2; ++mat) {
            const char* act = lds + (mat ? QH : PH);
            const int phase = mat ? 64 : 0;
            const unsigned short* WH = ws + mat * 16384;
            const float* bias = mat ? bk : bx;
            f32x4 acc[2][2] = {};
            for (int ks = 0; ks < 4; ++ks) {
                const int e0 = ks * 32 + l4 * 8;
                bf16x8 ah[2];
                #pragma unroll
                for (int nf = 0; nf < 2; ++nf)
                    ah[nf] = *(const bf16x8*)(act + swzp(n0 + nf * 16 + l15, e0 * 2, phase));
                #pragma unroll
                for (int mf = 0; mf < 2; ++mf) {
                    int orow = m0 + mf * 16 + l15;
                    bf16x8 wh = *(const bf16x8*)(WH + orow * 128 + e0);
                    #pragma unroll
                    for (int nf = 0; nf < 2; ++nf)
                        acc[mf][nf] = __builtin_amdgcn_mfma_f32_16x16x32_bf16(wh, ah[nf], acc[mf][nf], 0, 0, 0);
                }
            }
            #pragma unroll
            for (int mf = 0; mf < 2; ++mf) {
                int ob = m0 + mf * 16 + l4 * 4;
                f32x4 b4 = *(const f32x4*)(bias + ob);
                #pragma unroll
                for (int nf = 0; nf < 2; ++nf) {
                    u16x4 hs;
                    #pragma unroll
                    for (int r = 0; r < 4; ++r) hs[r] = cvt1(acc[mf][nf][r] + b4[r]);
                    if (mat) kpk[mf][nf] = hs; else xpk[mf][nf] = hs;
                }
            }
        }
    }
    __syncthreads();                 // B2: all activation-plane reads complete
    if (nact) {
        #pragma unroll
        for (int mf = 0; mf < 2; ++mf) {
            int ob2 = (m0 + mf * 16 + l4 * 4) * 2;
            #pragma unroll
            for (int nf = 0; nf < 2; ++nf) {
                int jrow = n0 + nf * 16 + l15;               // atom (D col)
                *(u16x4*)(lds + PH + swzp(jrow, ob2, 0))  = xpk[mf][nf];
                *(u16x4*)(lds + QH + swzp(jrow, ob2, 64)) = kpk[mf][nf];
            }
        }
    }
    __syncthreads();                 // B3: X,K planes ready

    // ---------------- P4: Grams (separate loops -> one 16-reg acc live during
    // each MFMA stretch) + pairwise epilogue
    const bool active = (m0 < count) && nact;
    if (active) {
        f32x4 gx[2][2] = {};
        for (int ks = 0; ks < 4; ++ks) {           // X gram
            const int e0b = (ks * 32 + l4 * 8) * 2;
            bf16x8 bX[2];
            #pragma unroll
            for (int nf = 0; nf < 2; ++nf)
                bX[nf] = *(const bf16x8*)(lds + PH + swzp(n0 + nf * 16 + l15, e0b, 0));
            #pragma unroll
            for (int mf = 0; mf < 2; ++mf) {
                bf16x8 aX = *(const bf16x8*)(lds + PH + swzp(m0 + mf * 16 + l15, e0b, 0));
                #pragma unroll
                for (int nf = 0; nf < 2; ++nf)
                    gx[mf][nf] = __builtin_amdgcn_mfma_f32_16x16x32_bf16(aX, bX[nf], gx[mf][nf], 0, 0, 0);
            }
        }
        f32x4 gk[2][2] = {};
        for (int ks = 0; ks < 4; ++ks) {           // K gram
            const int e0b = (ks * 32 + l4 * 8) * 2;
            bf16x8 bK[2];
            #pragma unroll
            for (int nf = 0; nf < 2; ++nf)
                bK[nf] = *(const bf16x8*)(lds + QH + swzp(n0 + nf * 16 + l15, e0b, 64));
            #pragma unroll
            for (int mf = 0; mf < 2; ++mf) {
                bf16x8 aK = *(const bf16x8*)(lds + QH + swzp(m0 + mf * 16 + l15, e0b, 64));
                #pragma unroll
                for (int nf = 0; nf < 2; ++nf)
                    gk[mf][nf] = __builtin_amdgcn_mfma_f32_16x16x32_bf16(aK, bK[nf], gk[mf][nf], 0, 0, 0);
            }
        }
        // pairwise epilogue on D-frags: lane's column j fixed per nf
        const float inv_e = 0.08838834764831845f;            // 1/sqrt(128)
        #pragma unroll
        for (int nf = 0; nf < 2; ++nf) {
            const int j = n0 + nf * 16 + l15;
            const bool jvalid = (j < count);
            const float pjx = posXs[j], pjy = posYs[j], pjz = posZs[j];
            float amx = 0.f, amy = 0.f, amz = 0.f;
            #pragma unroll
            for (int mf = 0; mf < 2; ++mf) {
                #pragma unroll
                for (int r = 0; r < 4; ++r) {
                    const int i = m0 + mf * 16 + l4 * 4 + r;
                    float dx = pjx - posXs[i];
                    float dy = pjy - posYs[i];
                    float dz = pjz - posZs[i];
                    float r2 = fmaf(dx, dx, fmaf(dy, dy, dz * dz)) + 1e-16f;
                    float rr = sqrtf(r2);
                    bool ok = jvalid && (i < count) && (rr < 5.0f);
                    float fc = ok ? (0.5f * (__cosf(rr * 0.62831853071795865f) + 1.f)) : 0.f;
                    float xs = fmaf(gx[mf][nf][r], -0.044194173824159216f, rr * 0.5f);
                    float fv = xs * (gk[mf][nf][r] * inv_e) * fc;
                    float wgt = fv / (rr + 1e-8f);
                    amx = fmaf(dx, wgt, amx);
                    amy = fmaf(dy, wgt, amy);
                    amz = fmaf(dz, wgt, amz);
                }
            }
            amx += __shfl_xor(amx, 16); amx += __shfl_xor(amx, 32);
            amy += __shfl_xor(amy, 16); amy += __shfl_xor(amy, 32);
            amz += __shfl_xor(amz, 16); amz += __shfl_xor(amz, 32);
            if (l4 == 0 && jvalid) {
                atomicAdd(&amBs[j * 3 + 0], amx);
                atomicAdd(&amBs[j * 3 + 1], amy);
                atomicAdd(&amBs[j * 3 + 2], amz);
            }
        }
    }
    __syncthreads();                 // B4: actions_mean complete

    // ---------------- P5: outputs
    if (t < 96) {
        f32x4 ev4 = *(const f32x4*)(evala + (size_t)b * 384 + t * 4);
        f32x4 o4;
        #pragma unroll
        for (int c = 0; c < 4; ++c) {
            int atom = (t * 4 + c) / 3;
            o4[c] = (atom < count) ? ev4[c] : 0.f;
        }
        *(f32x4*)(out + (size_t)b * 384 + t * 4) = o4;
    }
    float lp = 0.f;
    if (t < NATOM && t < count) {
        const float* ev = evala + ((size_t)b * NATOM + t) * 3;
        float e0v = ev[0], e1v = ev[1], e2v = ev[2];
        float scale = scale_ptr[0];
        float ax = amBs[t * 3 + 0], ay = amBs[t * 3 + 1], az = amBs[t * 3 + 2];
        float nrm = sqrtf(fmaf(ax, ax, fmaf(ay, ay, az * az)) + 1e-16f) + 1e-8f;
        float qe = __expf(-2.f * nrm);
        float th = (1.f - qe) / (1.f + qe);
        float sc = th / nrm * scale;
        float ls = fminf(fmaxf(lsBs[t], -20.f), 2.f);
        float sig = __expf(ls) * scale;
        float sinv = 1.f / sig;
        float zx = (e0v - ax * sc) * sinv;
        float zy = (e1v - ay * sc) * sinv;
        float zz = (e2v - az * sc) * sinv;
        lp = -0.5f * (zx * zx + zy * zy + zz * zz) - 3.f * __logf(sig)
             - 3.f * 0.91893853320467274f;
    }
    #pragma unroll
    for (int off = 32; off > 0; off >>= 1) lp += __shfl_down(lp, off);
    if (t == 0)  redBs[0] = lp;
    if (t == 64) redBs[1] = lp;
    __syncthreads();                 // B5
    if (t == 0) out[(size_t)NBATCH * NATOM * 3 + b] = redBs[0] + redBs[1];
}

extern "C" void kernel_launch(void* const* d_in, const int* in_sizes, int n_in,
                              void* d_out, int out_size, void* d_ws, size_t ws_size,
                              hipStream_t stream) {
    const float* kx    = (const float*)d_in[0];
    const float* pos   = (const float*)d_in[1];
    const float* mask  = (const float*)d_in[2];
    const float* scale = (const float*)d_in[3];
    const float* ev    = (const float*)d_in[4];
    const float* Wx    = (const float*)d_in[5];
    const float* bx    = (const float*)d_in[6];
    const float* Wk    = (const float*)d_in[7];
    const float* bk    = (const float*)d_in[8];
    float* out = (float*)d_out;
    unsigned short* ws = (unsigned short*)d_ws;

    // W -> bf16 (64KB in d_ws), recomputed each launch (deterministic)
    hipLaunchKernelGGL(wcvt_kernel, dim3(128), dim3(256), 0, stream, Wx, Wk, ws);

    const size_t shbytes = 65536;   // 2 planes x 32KB dynamic LDS -> 2 blocks/CU
    (void)hipFuncSetAttribute((const void*)gen_actions_kernel,
                              hipFuncAttributeMaxDynamicSharedMemorySize,
                              (int)shbytes);
    hipLaunchKernelGGL(gen_actions_kernel, dim3(NBATCH), dim3(THREADS), shbytes, stream,
                       kx, pos, mask, scale, ev, bx, bk, ws, out);
}

// Round 14
// 47.590 us; speedup vs baseline: 1.1288x; 1.0923x over previous
//
#include <hip/hip_runtime.h>
#include <math.h>

#define EDIM 128
#define NATOM 128
#define NBATCH 512
#define THREADS 1024
#define ROWLEN 257

typedef __attribute__((ext_vector_type(8))) short bf16x8;           // 8 bf16 (4 VGPRs)
typedef __attribute__((ext_vector_type(4))) float f32x4;            // MFMA C/D frag
typedef __attribute__((ext_vector_type(4))) unsigned short u16x4;   // 8B packed bf16

__device__ __forceinline__ unsigned short f2bf(float f) {       // RNE float->bf16
    unsigned u = __float_as_uint(f);
    u += 0x7FFFu + ((u >> 16) & 1u);
    return (unsigned short)(u >> 16);
}
// 1-op RNE f32->bf16 (single value)
__device__ __forceinline__ unsigned short cvt1(float x) {
    unsigned r;
    asm("v_cvt_pk_bf16_f32 %0, %1, %1" : "=v"(r) : "v"(x));
    return (unsigned short)r;
}
// 2-in-1 pack: dst[15:0]=bf16(a0), dst[31:16]=bf16(a1) -> memory order a0,a1
__device__ __forceinline__ unsigned cvt2(float a0, float a1) {
    unsigned r;
    asm("v_cvt_pk_bf16_f32 %0, %1, %2" : "=v"(r) : "v"(a0), "v"(a1));
    return r;
}
__device__ __forceinline__ float fast_ssp(float x) {            // softplus(x)-log2, stable
    return fmaxf(x, 0.f) + __logf(1.f + __expf(-fabsf(x))) - 0.69314718055994531f;
}
// XOR swizzle on a row-major [128][256B] bf16 plane (bits 4..6 of byte offset);
// consistent for b32 stores and b128 reads. phase decorrelates X vs K plane.
__device__ __forceinline__ int swzp(int row, int cbyte, int phase) {
    return row * 256 + ((cbyte ^ phase) ^ ((row & 7) << 4));
}

#define PH 0
#define QH 32768

// W -> bf16 (plain RNE; accuracy margin covers dropped lo-term: absmax 4.0 / thr 76.5)
__global__ void wcvt_kernel(const float* __restrict__ Wx,
                            const float* __restrict__ Wk,
                            unsigned short* __restrict__ ws) {
    int g = blockIdx.x * 256 + threadIdx.x;          // 0..32767
    const float* src = (g < 16384) ? Wx : Wk;
    ws[g] = f2bf(src[g & 16383]);
}

// 16 waves as 4x4 tile grid; each wave owns ONE 32x32 output tile. Per-mat GEMM
// write-back keeps P3 live state to acc(16)+pack(8) -> fits the (,8) 64-total-reg
// cap WITHOUT spill -> 8 waves/SIMD -> 2 blocks (32 waves) per CU.
__global__ void __launch_bounds__(THREADS, 8)
gen_actions_kernel(const float* __restrict__ kx,
                   const float* __restrict__ pos,
                   const float* __restrict__ mask,
                   const float* __restrict__ scale_ptr,
                   const float* __restrict__ evala,
                   const float* __restrict__ bx,
                   const float* __restrict__ bk,
                   const unsigned short* __restrict__ ws,
                   float* __restrict__ out)
{
    extern __shared__ char lds[];        // act_x/X plane (32KB) + act_k/K plane (32KB)
    __shared__ f32x4 posQs[NATOM];       // {x, y, z, log_std} -> 1 ds_read_b128 per atom
    __shared__ float amBs[NATOM * 3];
    __shared__ float redBs[2];
    __shared__ int   cntBs[2];

    const int b = blockIdx.x;
    const int t = threadIdx.x;
    const int lane = t & 63;
    const int w = t >> 6;            // wave 0..15
    const int wr = w >> 2;           // M tile (features / atoms-i), 0..3
    const int wc = w & 3;            // N tile (atoms-j), 0..3
    const int l15 = lane & 15;
    const int l4  = lane >> 4;

    // ---------------- P1: count, pos+log_std pack, zero accumulators
    if (t < NATOM) {
        float m = mask[b * NATOM + t];
        unsigned long long bal = __ballot(m > 0.5f);
        if ((t & 63) == 0) cntBs[t >> 6] = __popcll(bal);
        const float* p = pos + ((size_t)b * NATOM + t) * 3;
        f32x4 q;
        q[0] = p[0]; q[1] = p[1]; q[2] = p[2];
        q[3] = kx[(size_t)b * (NATOM * ROWLEN) + t * ROWLEN + 2 * EDIM];  // log_std
        posQs[t] = q;
    }
    if (t < NATOM * 3) amBs[t] = 0.f;

    // ---------------- P2: coalesced kx stream -> bf16 activation planes.
    // Per-wave redundant count (no barrier) skips rows >= ceil32(count) — exactly
    // the rows no tile reads. Lane handles adjacent pair (2e,2e+1): one cvt_pk +
    // one ds_write_b32 per plane per row. 8 rows/wave.
    {
        float mA = mask[b * NATOM + lane];
        float mB = mask[b * NATOM + 64 + lane];
        int cnt = __popcll(__ballot(mA > 0.5f)) + __popcll(__ballot(mB > 0.5f));
        const int cnt32 = (cnt + 31) & ~31;        // wave-uniform
        const float* kb = kx + (size_t)b * (NATOM * ROWLEN);
        #pragma unroll 4
        for (int r8 = 0; r8 < 8; ++r8) {
            const int row = r8 * 16 + w;
            if (row < cnt32) {                     // wave-uniform skip
                const float* src = kb + row * ROWLEN;
                float x0 = src[2 * lane];
                float x1 = src[2 * lane + 1];
                float y0 = src[128 + 2 * lane];
                float y1 = src[128 + 2 * lane + 1];
                unsigned pa = cvt2(fast_ssp(x0), fast_ssp(x1));
                unsigned pc = cvt2(fmaxf(y0, 0.f), fmaxf(y1, 0.f));
                *(unsigned*)(lds + PH + swzp(row, 4 * lane, 0))  = pa;
                *(unsigned*)(lds + QH + swzp(row, 4 * lane, 64)) = pc;
            }
        }
    }
    __syncthreads();                 // B1: planes + count + pos ready
    const int count = cntBs[0] + cntBs[1];   // mask is a contiguous prefix

    const int m0 = wr * 32;          // feature-tile base (GEMM) / atom-i tile (gram)
    const int n0 = wc * 32;          // atom-tile base (N-dim)
    const bool nact = (n0 < count);

    // ---------------- P3: X then K GEMM (bf16 W), per-mat write-back: live state
    // across the internal barrier is acc(16)+pack(8) only -> no spill at 64-reg cap.
    #define GEMM_MAT(PLANE, PHASE, WSOFF, BIAS)                                         \
    {                                                                                   \
        u16x4 pk[2][2];                                                                 \
        if (nact) {                                                                     \
            const char* act = lds + PLANE;                                              \
            const unsigned short* WH = ws + WSOFF;                                      \
            f32x4 acc[2][2] = {};                                                       \
            for (int ks = 0; ks < 4; ++ks) {                                            \
                const int e0 = ks * 32 + l4 * 8;                                        \
                bf16x8 ah[2];                                                           \
                _Pragma("unroll")                                                       \
                for (int nf = 0; nf < 2; ++nf)                                          \
                    ah[nf] = *(const bf16x8*)(act + swzp(n0 + nf * 16 + l15, e0 * 2, PHASE)); \
                _Pragma("unroll")                                                       \
                for (int mf = 0; mf < 2; ++mf) {                                        \
                    int orow = m0 + mf * 16 + l15;                                      \
                    bf16x8 wh = *(const bf16x8*)(WH + orow * 128 + e0);                 \
                    _Pragma("unroll")                                                   \
                    for (int nf = 0; nf < 2; ++nf)                                      \
                        acc[mf][nf] = __builtin_amdgcn_mfma_f32_16x16x32_bf16(wh, ah[nf], acc[mf][nf], 0, 0, 0); \
                }                                                                       \
            }                                                                           \
            _Pragma("unroll")                                                           \
            for (int mf = 0; mf < 2; ++mf) {                                            \
                int ob = m0 + mf * 16 + l4 * 4;                                         \
                f32x4 b4 = *(const f32x4*)(BIAS + ob);                                  \
                _Pragma("unroll")                                                       \
                for (int nf = 0; nf < 2; ++nf) {                                        \
                    u16x4 hs;                                                           \
                    _Pragma("unroll")                                                   \
                    for (int r = 0; r < 4; ++r) hs[r] = cvt1(acc[mf][nf][r] + b4[r]);   \
                    pk[mf][nf] = hs;                                                    \
                }                                                                       \
            }                                                                           \
        }                                                                               \
        __syncthreads();   /* all reads of this act plane complete */                   \
        if (nact) {                                                                     \
            _Pragma("unroll")                                                           \
            for (int mf = 0; mf < 2; ++mf) {                                            \
                int ob2 = (m0 + mf * 16 + l4 * 4) * 2;                                  \
                _Pragma("unroll")                                                       \
                for (int nf = 0; nf < 2; ++nf) {                                        \
                    int jrow = n0 + nf * 16 + l15;                                      \
                    *(u16x4*)(lds + PLANE + swzp(jrow, ob2, PHASE)) = pk[mf][nf];       \
                }                                                                       \
            }                                                                           \
        }                                                                               \
    }

    GEMM_MAT(PH, 0,  0,     bx)      // X written to PH
    GEMM_MAT(QH, 64, 16384, bk)      // K written to QH
    __syncthreads();                 // B3: X,K planes ready

    // ---------------- P4: Grams (separate loops -> one 16-reg acc live per MFMA
    // stretch) + pairwise epilogue
    const bool active = (m0 < count) && nact;
    if (active) {
        f32x4 gx[2][2] = {};
        for (int ks = 0; ks < 4; ++ks) {           // X gram
            const int e0b = (ks * 32 + l4 * 8) * 2;
            bf16x8 bX[2];
            #pragma unroll
            for (int nf = 0; nf < 2; ++nf)
                bX[nf] = *(const bf16x8*)(lds + PH + swzp(n0 + nf * 16 + l15, e0b, 0));
            #pragma unroll
            for (int mf = 0; mf < 2; ++mf) {
                bf16x8 aX = *(const bf16x8*)(lds + PH + swzp(m0 + mf * 16 + l15, e0b, 0));
                #pragma unroll
                for (int nf = 0; nf < 2; ++nf)
                    gx[mf][nf] = __builtin_amdgcn_mfma_f32_16x16x32_bf16(aX, bX[nf], gx[mf][nf], 0, 0, 0);
            }
        }
        f32x4 gk[2][2] = {};
        for (int ks = 0; ks < 4; ++ks) {           // K gram
            const int e0b = (ks * 32 + l4 * 8) * 2;
            bf16x8 bK[2];
            #pragma unroll
            for (int nf = 0; nf < 2; ++nf)
                bK[nf] = *(const bf16x8*)(lds + QH + swzp(n0 + nf * 16 + l15, e0b, 64));
            #pragma unroll
            for (int mf = 0; mf < 2; ++mf) {
                bf16x8 aK = *(const bf16x8*)(lds + QH + swzp(m0 + mf * 16 + l15, e0b, 64));
                #pragma unroll
                for (int nf = 0; nf < 2; ++nf)
                    gk[mf][nf] = __builtin_amdgcn_mfma_f32_16x16x32_bf16(aK, bK[nf], gk[mf][nf], 0, 0, 0);
            }
        }
        // pairwise epilogue: i-outer (1 ds_read_b128 posQ per i), nf-inner;
        // fast rcp/sqrt (err ~1e-7; margin 76.5/4.0) — validated in R12.
        const float inv_e = 0.08838834764831845f;            // 1/sqrt(128)
        float am[2][3] = {};
        f32x4 pj4[2];
        bool jv[2];
        #pragma unroll
        for (int nf = 0; nf < 2; ++nf) {
            const int j = n0 + nf * 16 + l15;
            jv[nf] = (j < count);
            pj4[nf] = posQs[j];
        }
        #pragma unroll
        for (int mf = 0; mf < 2; ++mf) {
            #pragma unroll
            for (int r = 0; r < 4; ++r) {
                const int i = m0 + mf * 16 + l4 * 4 + r;
                f32x4 pi4 = posQs[i];
                const bool iv = (i < count);
                #pragma unroll
                for (int nf = 0; nf < 2; ++nf) {
                    float dx = pj4[nf][0] - pi4[0];
                    float dy = pj4[nf][1] - pi4[1];
                    float dz = pj4[nf][2] - pi4[2];
                    float r2 = fmaf(dx, dx, fmaf(dy, dy, dz * dz)) + 1e-16f;
                    float rr = __builtin_amdgcn_sqrtf(r2);
                    bool ok = jv[nf] && iv && (rr < 5.0f);
                    float fc = ok ? (0.5f * (__cosf(rr * 0.62831853071795865f) + 1.f)) : 0.f;
                    float xs = fmaf(gx[mf][nf][r], -0.044194173824159216f, rr * 0.5f);
                    float fv = xs * (gk[mf][nf][r] * inv_e) * fc;
                    float wgt = fv * __builtin_amdgcn_rcpf(rr + 1e-8f);
                    am[nf][0] = fmaf(dx, wgt, am[nf][0]);
                    am[nf][1] = fmaf(dy, wgt, am[nf][1]);
                    am[nf][2] = fmaf(dz, wgt, am[nf][2]);
                }
            }
        }
        #pragma unroll
        for (int nf = 0; nf < 2; ++nf) {
            float amx = am[nf][0], amy = am[nf][1], amz = am[nf][2];
            amx += __shfl_xor(amx, 16); amx += __shfl_xor(amx, 32);
            amy += __shfl_xor(amy, 16); amy += __shfl_xor(amy, 32);
            amz += __shfl_xor(amz, 16); amz += __shfl_xor(amz, 32);
            if (l4 == 0 && jv[nf]) {
                const int j = n0 + nf * 16 + l15;
                atomicAdd(&amBs[j * 3 + 0], amx);
                atomicAdd(&amBs[j * 3 + 1], amy);
                atomicAdd(&amBs[j * 3 + 2], amz);
            }
        }
    }
    __syncthreads();                 // B4: actions_mean complete

    // ---------------- P5: outputs
    if (t < 96) {
        f32x4 ev4 = *(const f32x4*)(evala + (size_t)b * 384 + t * 4);
        f32x4 o4;
        #pragma unroll
        for (int c = 0; c < 4; ++c) {
            int atom = (t * 4 + c) / 3;
            o4[c] = (atom < count) ? ev4[c] : 0.f;
        }
        *(f32x4*)(out + (size_t)b * 384 + t * 4) = o4;
    }
    float lp = 0.f;
    if (t < NATOM && t < count) {
        const float* ev = evala + ((size_t)b * NATOM + t) * 3;
        float e0v = ev[0], e1v = ev[1], e2v = ev[2];
        float scale = scale_ptr[0];
        f32x4 q = posQs[t];
        float ax = amBs[t * 3 + 0], ay = amBs[t * 3 + 1], az = amBs[t * 3 + 2];
        float nrm = sqrtf(fmaf(ax, ax, fmaf(ay, ay, az * az)) + 1e-16f) + 1e-8f;
        float qe = __expf(-2.f * nrm);
        float th = (1.f - qe) / (1.f + qe);
        float sc = th / nrm * scale;
        float ls = fminf(fmaxf(q[3], -20.f), 2.f);
        float sig = __expf(ls) * scale;
        float sinv = 1.f / sig;
        float zx = (e0v - ax * sc) * sinv;
        float zy = (e1v - ay * sc) * sinv;
        float zz = (e2v - az * sc) * sinv;
        lp = -0.5f * (zx * zx + zy * zy + zz * zz) - 3.f * __logf(sig)
             - 3.f * 0.91893853320467274f;
    }
    #pragma unroll
    for (int off = 32; off > 0; off >>= 1) lp += __shfl_down(lp, off);
    if (t == 0)  redBs[0] = lp;
    if (t == 64) redBs[1] = lp;
    __syncthreads();                 // B5
    if (t == 0) out[(size_t)NBATCH * NATOM * 3 + b] = redBs[0] + redBs[1];
}

extern "C" void kernel_launch(void* const* d_in, const int* in_sizes, int n_in,
                              void* d_out, int out_size, void* d_ws, size_t ws_size,
                              hipStream_t stream) {
    const float* kx    = (const float*)d_in[0];
    const float* pos   = (const float*)d_in[1];
    const float* mask  = (const float*)d_in[2];
    const float* scale = (const float*)d_in[3];
    const float* ev    = (const float*)d_in[4];
    const float* Wx    = (const float*)d_in[5];
    const float* bx    = (const float*)d_in[6];
    const float* Wk    = (const float*)d_in[7];
    const float* bk    = (const float*)d_in[8];
    float* out = (float*)d_out;
    unsigned short* ws = (unsigned short*)d_ws;

    // W -> bf16 (64KB in d_ws), recomputed each launch (deterministic)
    hipLaunchKernelGGL(wcvt_kernel, dim3(128), dim3(256), 0, stream, Wx, Wk, ws);

    const size_t shbytes = 65536;   // 2 planes x 32KB dynamic LDS -> 2 blocks/CU
    (void)hipFuncSetAttribute((const void*)gen_actions_kernel,
                              hipFuncAttributeMaxDynamicSharedMemorySize,
                              (int)shbytes);
    hipLaunchKernelGGL(gen_actions_kernel, dim3(NBATCH), dim3(THREADS), shbytes, stream,
                       kx, pos, mask, scale, ev, bx, bk, ws, out);
}